// Round 2
// baseline (1003.492 us; speedup 1.0000x reference)
//
#include <hip/hip_runtime.h>

#define Bb 256
#define Tt 1024
#define NT 96

// CRF forward (log partition) — one block per batch element, 256 threads.
// Thread (i = tid>>1, q = tid&1) owns E[i][q*48..q*48+47] = exp(trans) in VGPRs.
// Linear-space recurrence with predictive normalizer:
//   v[i]   = sum_j E[i,j] * p[j]              (48 FMA + 1 shfl_xor per thread)
//   p'[i]  = v[i] * exp(h_t[i]) * u_t         (exp(h) prefetched 2 steps ahead)
//   u_t    = e^{-c} / (W_{t-1} * u_{t-1}),  W_t = max_i(v[i]*exp(h_t[i]))
//   M     += -log(u_t)                         (off critical path)
// Stability: stored-exponent scale delta_{t+1} = beta_t - c, beta_t bounded by
// current-step quantities only (no feedback oscillator). One barrier per step.
__global__ __launch_bounds__(256, 1) void crf_fwd_kernel(
    const float* __restrict__ h,       // [B][T][NT]
    const int*   __restrict__ lengths, // [B]
    const float* __restrict__ trans,   // [NT][NT] trans[to, from]
    float* __restrict__ out)           // [B]
{
    const int b    = blockIdx.x;
    const int tid  = threadIdx.x;
    const int i    = tid >> 1;
    const int q    = tid & 1;
    const int L    = lengths[b];
    const bool active = (i < NT);
    const int wave = tid >> 6;

    __shared__ float  p_lds[2][128];
    __shared__ float4 redv[2];
    __shared__ float  fin[4];

    // E = exp(trans) row segment, in registers
    float E[48];
    if (active) {
        const float* tr = trans + i * NT + q * 48;
        #pragma unroll
        for (int k = 0; k < 48; ++k) E[k] = __expf(tr[k]);
    } else {
        #pragma unroll
        for (int k = 0; k < 48; ++k) E[k] = 0.0f;
    }

    // p_0 = delta(start_tag); exp(-10000)==0 in fp32 matches reference
    if (tid < 128) p_lds[0][tid] = (tid == NT - 2) ? 1.0f : 0.0f;
    if (tid == 0) {
        redv[0] = make_float4(1.f, 1.f, 1.f, 1.f);
        redv[1] = make_float4(1.f, 1.f, 1.f, 1.f);
    }

    const float* hb = h + (size_t)b * Tt * NT;
    // prefetch exp(h) for t=0 and t=1 (2-step pipeline)
    float eh0 = active ? __expf(hb[i]) : 1.0f;
    float eh1 = active ? __expf(hb[(size_t)((L > 1) ? 1 : 0) * NT + i]) : 1.0f;

    const float c = 6.0f;
    const float Kc = __expf(-c);
    float u_prev = 1.0f;
    float M = 0.0f;
    float p_keep = 0.0f;

    __syncthreads();

    int cur = 0;
    for (int t = 0; t < L; ++t) {
        // issue normalizer read first (latency overlaps the dot product)
        const float4 r4 = redv[cur];

        // v[i] over this thread's j-half, vectorized LDS reads
        const float4* pv = reinterpret_cast<const float4*>(p_lds[cur] + q * 48);
        float a0 = 0.f, a1 = 0.f, a2 = 0.f, a3 = 0.f;
        #pragma unroll
        for (int k = 0; k < 12; ++k) {
            const float4 p4 = pv[k];
            a0 = fmaf(E[4*k+0], p4.x, a0);
            a1 = fmaf(E[4*k+1], p4.y, a1);
            a2 = fmaf(E[4*k+2], p4.z, a2);
            a3 = fmaf(E[4*k+3], p4.w, a3);
        }
        float v = (a0 + a1) + (a2 + a3);
        v += __shfl_xor(v, 1, 64);          // combine the two j-halves

        const float Wp = fmaxf(fmaxf(r4.x, r4.y), fmaxf(r4.z, r4.w));
        const float u  = Kc * __builtin_amdgcn_rcpf(Wp * u_prev);

        const float w  = v * eh0;           // = exp(raw_t[i])
        const float pn = w * u;

        // wave-level max of w (pairs hold duplicates, so strides 2..32)
        float wm = w;
        #pragma unroll
        for (int s = 2; s < 64; s <<= 1) wm = fmaxf(wm, __shfl_xor(wm, s, 64));

        const int nxt = cur ^ 1;
        if (active && q == 0) {
            p_lds[nxt][i] = pn;
            p_keep = pn;
        }
        if ((tid & 63) == 0) ((float*)&redv[nxt])[wave] = wm;

        M -= __logf(u);                     // off critical path
        u_prev = u;

        // rotate exp(h) prefetch: bring in t+2 (clamped)
        eh0 = eh1;
        int tn = t + 2; if (tn > L - 1) tn = L - 1;
        eh1 = active ? __expf(hb[(size_t)tn * NT + i]) : 1.0f;

        __syncthreads();                    // single barrier per step
        cur = nxt;
    }

    // out[b] = M + log( sum_i p_L[i] * exp(trans[end_tag, i]) )
    float term = (active && q == 0) ? p_keep * __expf(trans[(NT - 1) * NT + i]) : 0.0f;
    #pragma unroll
    for (int s = 1; s < 64; s <<= 1) term += __shfl_xor(term, s, 64);
    if ((tid & 63) == 0) fin[wave] = term;
    __syncthreads();
    if (tid == 0) out[b] = M + __logf(fin[0] + fin[1] + fin[2] + fin[3]);
}

extern "C" void kernel_launch(void* const* d_in, const int* in_sizes, int n_in,
                              void* d_out, int out_size, void* d_ws, size_t ws_size,
                              hipStream_t stream) {
    const float* h       = (const float*)d_in[0];
    const int*   lengths = (const int*)d_in[1];
    const float* trans   = (const float*)d_in[2];
    float*       out     = (float*)d_out;
    (void)in_sizes; (void)n_in; (void)out_size; (void)d_ws; (void)ws_size;

    crf_fwd_kernel<<<Bb, 256, 0, stream>>>(h, lengths, trans, out);
}

// Round 3
// 405.464 us; speedup vs baseline: 2.4749x; 2.4749x over previous
//
#include <hip/hip_runtime.h>

#define Bb 256
#define Tt 1024
#define NT 96
#define PF 8   // h-prefetch depth (static rotating registers, loop unrolled by PF)

// CRF forward (log partition) — one block per batch element, 256 threads.
// Thread (i = tid>>1, q = tid&1) owns E[i][q*48..q*48+47] = exp(trans) in VGPRs.
// Linear-space recurrence, feed-forward normalizer read straight from LDS:
//   v[i]  = sum_j E[i,j] * p[j]          (48 FMA + 1 shfl_xor per thread)
//   w[i]  = v[i] * exp(h_t[i])
//   u     = e^{-c} / p_prev[0]           (tag-0 probe; u=1 at t=0)
//   p'[i] = masked(t<L) ? w[i]*u : p[i]
//   M    -= masked ? log(u) : 0
// Stored exponent = S_{t+1}[i] - S_t[0] - c: bounded by current-step spread
// only (no feedback). Fixed 1024-step loop (masked steps are selects), so the
// body unrolls by PF and keeps PF h-loads in flight (HBM latency hidden).
__global__ __launch_bounds__(256, 1) void crf_fwd_kernel(
    const float* __restrict__ h,       // [B][T][NT]
    const int*   __restrict__ lengths, // [B]
    const float* __restrict__ trans,   // [NT][NT] trans[to, from]
    float* __restrict__ out)           // [B]
{
    const int b    = blockIdx.x;
    const int tid  = threadIdx.x;
    const int i    = tid >> 1;
    const int q    = tid & 1;
    const int L    = lengths[b];
    const bool active = (i < NT);
    const int wave = tid >> 6;

    __shared__ float p_lds[2][128];
    __shared__ float fin[4];

    // E = exp(trans) row segment, in registers
    float E[48];
    if (active) {
        const float* tr = trans + i * NT + q * 48;
        #pragma unroll
        for (int k = 0; k < 48; ++k) E[k] = __expf(tr[k]);
    } else {
        #pragma unroll
        for (int k = 0; k < 48; ++k) E[k] = 0.0f;
    }

    // p_0 = delta(start_tag); exp(-10000)==0 in fp32 matches reference
    if (tid < 128) p_lds[0][tid] = (tid == NT - 2) ? 1.0f : 0.0f;

    const float* hb = h + (size_t)b * Tt * NT;

    // PF-deep raw-h prefetch (static rotation via full unroll)
    float hp[PF];
    #pragma unroll
    for (int k = 0; k < PF; ++k)
        hp[k] = active ? hb[(size_t)k * NT + i] : 0.0f;

    const float c  = 4.0f;
    const float Kc = __expf(-c);
    float M = 0.0f;
    float p_keep = 0.0f;

    __syncthreads();

    int cur = 0;
    for (int tb = 0; tb < Tt; tb += PF) {
        #pragma unroll
        for (int k = 0; k < PF; ++k) {
            const int t = tb + k;

            // normalizer probe (broadcast LDS read, overlaps the dot product)
            const float p0 = p_lds[cur][0];

            // v[i] over this thread's j-half, vectorized broadcast LDS reads
            const float4* pv = reinterpret_cast<const float4*>(p_lds[cur] + q * 48);
            float a0 = 0.f, a1 = 0.f, a2 = 0.f, a3 = 0.f;
            #pragma unroll
            for (int m = 0; m < 12; ++m) {
                const float4 p4 = pv[m];
                a0 = fmaf(E[4*m+0], p4.x, a0);
                a1 = fmaf(E[4*m+1], p4.y, a1);
                a2 = fmaf(E[4*m+2], p4.z, a2);
                a3 = fmaf(E[4*m+3], p4.w, a3);
            }
            float v = (a0 + a1) + (a2 + a3);
            v += __shfl_xor(v, 1, 64);          // combine the two j-halves

            const float eh = __expf(hp[k]);
            // reissue prefetch for t+PF (clamped; always-run loop reads all T)
            int tn = t + PF; if (tn > Tt - 1) tn = Tt - 1;
            hp[k] = active ? hb[(size_t)tn * NT + i] : 0.0f;

            const float u  = (t == 0) ? 1.0f : Kc * __builtin_amdgcn_rcpf(p0);
            const float w  = v * eh;
            const bool msk = (t < L);
            const float pn = msk ? (w * u) : p_keep;   // masked step: keep score
            M -= msk ? __logf(u) : 0.0f;
            p_keep = pn;

            const int nxt = cur ^ 1;
            if (active && q == 0) p_lds[nxt][i] = pn;

            __syncthreads();                    // single barrier per step
            cur = nxt;
        }
    }

    // out[b] = M + log( sum_i p_L[i] * exp(trans[end_tag, i]) )
    float term = (active && q == 0) ? p_keep * __expf(trans[(NT - 1) * NT + i]) : 0.0f;
    #pragma unroll
    for (int s = 1; s < 64; s <<= 1) term += __shfl_xor(term, s, 64);
    if ((tid & 63) == 0) fin[wave] = term;
    __syncthreads();
    if (tid == 0) out[b] = M + __logf(fin[0] + fin[1] + fin[2] + fin[3]);
}

extern "C" void kernel_launch(void* const* d_in, const int* in_sizes, int n_in,
                              void* d_out, int out_size, void* d_ws, size_t ws_size,
                              hipStream_t stream) {
    const float* h       = (const float*)d_in[0];
    const int*   lengths = (const int*)d_in[1];
    const float* trans   = (const float*)d_in[2];
    float*       out     = (float*)d_out;
    (void)in_sizes; (void)n_in; (void)out_size; (void)d_ws; (void)ws_size;

    crf_fwd_kernel<<<Bb, 256, 0, stream>>>(h, lengths, trans, out);
}

// Round 4
// 382.280 us; speedup vs baseline: 2.6250x; 1.0606x over previous
//
#include <hip/hip_runtime.h>

#define Bb 256
#define Tt 1024
#define NT 96
#define PF 8   // prefetch batch; double-buffered => 16 steps of load slack

// CRF forward (log partition) — one block per batch element, 256 threads.
// Thread (i = tid>>1, q = tid&1) owns E[i][q*48..q*48+47] = exp(trans) in VGPRs.
// Linear-space recurrence, feed-forward normalizer (tag-0 probe):
//   v[i]  = sum_j E[i,j] * p[j];  w = v * exp(h_t[i]);  u = e^{-c}/p_prev[0]
//   p'[i] = (t<L) ? w*u : p[i];   M -= (t<L) ? log(u) : 0
// KEY: __syncthreads() would emit s_waitcnt vmcnt(0) before s_barrier and
// drain the h prefetch every step (~600cy). We barrier with an explicit
// lgkmcnt(0)-only fence (LDS is the only cross-wave dep; h is read-only),
// so global loads stay in flight across barriers (counted vmcnt at use).
__global__ __launch_bounds__(256, 1) void crf_fwd_kernel(
    const float* __restrict__ h,       // [B][T][NT]
    const int*   __restrict__ lengths, // [B]
    const float* __restrict__ trans,   // [NT][NT] trans[to, from]
    float* __restrict__ out)           // [B]
{
    const int b    = blockIdx.x;
    const int tid  = threadIdx.x;
    const int i    = tid >> 1;
    const int q    = tid & 1;
    const int L    = lengths[b];
    const bool active = (i < NT);
    const int wave = tid >> 6;

    __shared__ float p_lds[2][128];
    __shared__ float fin[4];

    // E = exp(trans) row segment, in registers
    float E[48];
    if (active) {
        const float* tr = trans + i * NT + q * 48;
        #pragma unroll
        for (int k = 0; k < 48; ++k) E[k] = __expf(tr[k]);
    } else {
        #pragma unroll
        for (int k = 0; k < 48; ++k) E[k] = 0.0f;
    }

    // p_0 = delta(start_tag); exp(-10000)==0 in fp32 matches reference
    if (tid < 128) p_lds[0][tid] = (tid == NT - 2) ? 1.0f : 0.0f;

    const float* hb  = h + (size_t)b * Tt * NT;
    const float* hld = active ? (hb + i) : hb;   // safe base, no per-step select

    // double-buffered 8-deep prefetch: hpA <- t 0..7, hpB <- t 8..15
    float hpA[PF], hpB[PF];
    #pragma unroll
    for (int k = 0; k < PF; ++k) hpA[k] = hld[(size_t)k * NT];
    #pragma unroll
    for (int k = 0; k < PF; ++k) hpB[k] = hld[(size_t)(PF + k) * NT];

    const float c  = 4.0f;
    const float Kc = __expf(-c);
    float M = 0.0f;
    float p_keep = 0.0f;

    __syncthreads();   // one-time init sync (drain here is harmless)

    int cur = 0;

#define STEP(HREG, T_)                                                        \
    {                                                                         \
        const float p0 = p_lds[cur][0];                                       \
        const float4* pv = reinterpret_cast<const float4*>(p_lds[cur] + q*48);\
        float a0 = 0.f, a1 = 0.f, a2 = 0.f, a3 = 0.f;                         \
        _Pragma("unroll")                                                     \
        for (int m_ = 0; m_ < 12; ++m_) {                                     \
            const float4 p4 = pv[m_];                                         \
            a0 = fmaf(E[4*m_+0], p4.x, a0);                                   \
            a1 = fmaf(E[4*m_+1], p4.y, a1);                                   \
            a2 = fmaf(E[4*m_+2], p4.z, a2);                                   \
            a3 = fmaf(E[4*m_+3], p4.w, a3);                                   \
        }                                                                     \
        float v = (a0 + a1) + (a2 + a3);                                      \
        v += __shfl_xor(v, 1, 64);                                            \
        const float eh = __expf(HREG);                                        \
        const float u  = ((T_) == 0) ? 1.0f : Kc * __builtin_amdgcn_rcpf(p0); \
        const float w  = v * eh;                                              \
        const bool msk = ((T_) < L);                                          \
        const float pn = msk ? (w * u) : p_keep;                              \
        M -= msk ? __logf(u) : 0.0f;                                          \
        p_keep = pn;                                                          \
        if (active && q == 0) p_lds[cur ^ 1][i] = pn;                         \
        asm volatile("s_waitcnt lgkmcnt(0)" ::: "memory");                    \
        __builtin_amdgcn_s_barrier();                                         \
        asm volatile("" ::: "memory");                                        \
        cur ^= 1;                                                             \
    }

    for (int tb = 0; tb < Tt; tb += 2 * PF) {
        #pragma unroll
        for (int k = 0; k < PF; ++k) STEP(hpA[k], tb + k);

        // reload hpA <- t = tb+16 .. tb+23 (clamped); in flight for 8 steps
        #pragma unroll
        for (int m = 0; m < PF; ++m) {
            int tn = tb + 2 * PF + m; if (tn > Tt - 1) tn = Tt - 1;
            hpA[m] = hld[(size_t)tn * NT];
        }

        #pragma unroll
        for (int k = 0; k < PF; ++k) STEP(hpB[k], tb + PF + k);

        // reload hpB <- t = tb+24 .. tb+31 (clamped)
        #pragma unroll
        for (int m = 0; m < PF; ++m) {
            int tn = tb + 3 * PF + m; if (tn > Tt - 1) tn = Tt - 1;
            hpB[m] = hld[(size_t)tn * NT];
        }
    }
#undef STEP

    // out[b] = M + log( sum_i p_L[i] * exp(trans[end_tag, i]) )
    float term = (active && q == 0) ? p_keep * __expf(trans[(NT - 1) * NT + i]) : 0.0f;
    #pragma unroll
    for (int s = 1; s < 64; s <<= 1) term += __shfl_xor(term, s, 64);
    if ((tid & 63) == 0) fin[wave] = term;
    __syncthreads();
    if (tid == 0) out[b] = M + __logf(fin[0] + fin[1] + fin[2] + fin[3]);
}

extern "C" void kernel_launch(void* const* d_in, const int* in_sizes, int n_in,
                              void* d_out, int out_size, void* d_ws, size_t ws_size,
                              hipStream_t stream) {
    const float* h       = (const float*)d_in[0];
    const int*   lengths = (const int*)d_in[1];
    const float* trans   = (const float*)d_in[2];
    float*       out     = (float*)d_out;
    (void)in_sizes; (void)n_in; (void)out_size; (void)d_ws; (void)ws_size;

    crf_fwd_kernel<<<Bb, 256, 0, stream>>>(h, lengths, trans, out);
}

// Round 6
// 381.296 us; speedup vs baseline: 2.6318x; 1.0026x over previous
//
#include <hip/hip_runtime.h>

#define Bb 256
#define Tt 1024
#define NT 96
#define PF 8   // prefetch batch; double-buffered => up to 16 steps of load slack

// CRF forward (log partition) — one block per batch element, 256 threads.
// Thread (i = tid>>1, q = tid&1) owns E[i][q*48..q*48+47] = exp(trans) as 48
// scalar VGPRs, PINNED via scalar "+v" asm ties (float4 ties don't compile:
// "tied indirect register inputs"). Round-4 evidence: VGPR_Count=56 => E was
// being rematerialized (trans reload + 48x v_exp_f32) every step.
// amdgpu_waves_per_eu(1,1) gives the full 512-VGPR budget.
// Linear-space recurrence, feed-forward normalizer (tag-0 probe):
//   v[i]  = sum_j E[i,j] * p[j];  w = v * exp(h_t[i]);  u = e^{-c}/p_prev[0]
//   p'[i] = (t<L) ? w*u : p[i];   M -= (t<L) ? log(u) : 0
// Barrier = lgkmcnt(0)-only fence + s_barrier (no vmcnt drain => h prefetch
// stays in flight across steps).
__global__ __attribute__((amdgpu_flat_work_group_size(256, 256),
                          amdgpu_waves_per_eu(1, 1)))
void crf_fwd_kernel(
    const float* __restrict__ h,       // [B][T][NT]
    const int*   __restrict__ lengths, // [B]
    const float* __restrict__ trans,   // [NT][NT] trans[to, from]
    float* __restrict__ out)           // [B]
{
    const int b    = blockIdx.x;
    const int tid  = threadIdx.x;
    const int i    = tid >> 1;
    const int q    = tid & 1;
    const int L    = lengths[b];
    const bool active = (i < NT);
    const int wave = tid >> 6;

    __shared__ float p_lds[2][128];
    __shared__ float fin[4];

    // E = exp(trans) row segment as 48 scalars (SROA -> 48 VGPRs), pinned.
    // Inactive lanes load row 0 (in-bounds); their results are never consumed.
    float E[48];
    {
        const int ic = active ? i : 0;
        const float4* tr4 = reinterpret_cast<const float4*>(trans + ic * NT + q * 48);
        #pragma unroll
        for (int m = 0; m < 12; ++m) {
            const float4 t4 = tr4[m];
            E[4*m+0] = __expf(t4.x);
            E[4*m+1] = __expf(t4.y);
            E[4*m+2] = __expf(t4.z);
            E[4*m+3] = __expf(t4.w);
        }
    }
    // Pin: asm-defined scalars cannot be rematerialized or sunk into the loop.
    asm volatile("" : "+v"(E[0]),  "+v"(E[1]),  "+v"(E[2]),  "+v"(E[3]),
                      "+v"(E[4]),  "+v"(E[5]),  "+v"(E[6]),  "+v"(E[7]),
                      "+v"(E[8]),  "+v"(E[9]),  "+v"(E[10]), "+v"(E[11]));
    asm volatile("" : "+v"(E[12]), "+v"(E[13]), "+v"(E[14]), "+v"(E[15]),
                      "+v"(E[16]), "+v"(E[17]), "+v"(E[18]), "+v"(E[19]),
                      "+v"(E[20]), "+v"(E[21]), "+v"(E[22]), "+v"(E[23]));
    asm volatile("" : "+v"(E[24]), "+v"(E[25]), "+v"(E[26]), "+v"(E[27]),
                      "+v"(E[28]), "+v"(E[29]), "+v"(E[30]), "+v"(E[31]),
                      "+v"(E[32]), "+v"(E[33]), "+v"(E[34]), "+v"(E[35]));
    asm volatile("" : "+v"(E[36]), "+v"(E[37]), "+v"(E[38]), "+v"(E[39]),
                      "+v"(E[40]), "+v"(E[41]), "+v"(E[42]), "+v"(E[43]),
                      "+v"(E[44]), "+v"(E[45]), "+v"(E[46]), "+v"(E[47]));

    // p_0 = delta(start_tag); exp(-10000)==0 in fp32 matches reference
    if (tid < 128) p_lds[0][tid] = (tid == NT - 2) ? 1.0f : 0.0f;

    const float* hb  = h + (size_t)b * Tt * NT;
    const float* hld = active ? (hb + i) : hb;   // safe base, no per-step select

    // double-buffered 8-deep prefetch: hpA <- t 0..7, hpB <- t 8..15
    float hpA[PF], hpB[PF];
    #pragma unroll
    for (int k = 0; k < PF; ++k) hpA[k] = hld[(size_t)k * NT];
    #pragma unroll
    for (int k = 0; k < PF; ++k) hpB[k] = hld[(size_t)(PF + k) * NT];

    const float c  = 4.0f;
    const float Kc = __expf(-c);
    float M = 0.0f;
    float p_keep = 0.0f;

    __syncthreads();   // one-time init sync (drain here is harmless)

    int cur = 0;

#define STEP(HREG, T_)                                                        \
    {                                                                         \
        const float p0 = p_lds[cur][0];                                       \
        const float4* pv = reinterpret_cast<const float4*>(p_lds[cur] + q*48);\
        float a0 = 0.f, a1 = 0.f, a2 = 0.f, a3 = 0.f;                         \
        _Pragma("unroll")                                                     \
        for (int m_ = 0; m_ < 12; ++m_) {                                     \
            const float4 p4 = pv[m_];                                         \
            a0 = fmaf(E[4*m_+0], p4.x, a0);                                   \
            a1 = fmaf(E[4*m_+1], p4.y, a1);                                   \
            a2 = fmaf(E[4*m_+2], p4.z, a2);                                   \
            a3 = fmaf(E[4*m_+3], p4.w, a3);                                   \
        }                                                                     \
        float v = (a0 + a1) + (a2 + a3);                                      \
        v += __shfl_xor(v, 1, 64);                                            \
        const float eh = __expf(HREG);                                        \
        const float u  = ((T_) == 0) ? 1.0f : Kc * __builtin_amdgcn_rcpf(p0); \
        const float w  = v * eh;                                              \
        const bool msk = ((T_) < L);                                          \
        const float pn = msk ? (w * u) : p_keep;                              \
        M -= msk ? __logf(u) : 0.0f;                                          \
        p_keep = pn;                                                          \
        if (active && q == 0) p_lds[cur ^ 1][i] = pn;                         \
        asm volatile("s_waitcnt lgkmcnt(0)" ::: "memory");                    \
        __builtin_amdgcn_s_barrier();                                         \
        asm volatile("" ::: "memory");                                        \
        cur ^= 1;                                                             \
    }

    for (int tb = 0; tb < Tt; tb += 2 * PF) {
        #pragma unroll
        for (int k = 0; k < PF; ++k) STEP(hpA[k], tb + k);

        // reload hpA <- t = tb+16 .. tb+23 (clamped); in flight for 8 steps
        #pragma unroll
        for (int m = 0; m < PF; ++m) {
            int tn = tb + 2 * PF + m; if (tn > Tt - 1) tn = Tt - 1;
            hpA[m] = hld[(size_t)tn * NT];
        }

        #pragma unroll
        for (int k = 0; k < PF; ++k) STEP(hpB[k], tb + PF + k);

        // reload hpB <- t = tb+24 .. tb+31 (clamped)
        #pragma unroll
        for (int m = 0; m < PF; ++m) {
            int tn = tb + 3 * PF + m; if (tn > Tt - 1) tn = Tt - 1;
            hpB[m] = hld[(size_t)tn * NT];
        }
    }
#undef STEP

    // out[b] = M + log( sum_i p_L[i] * exp(trans[end_tag, i]) )
    float term = (active && q == 0) ? p_keep * __expf(trans[(NT - 1) * NT + i]) : 0.0f;
    #pragma unroll
    for (int s = 1; s < 64; s <<= 1) term += __shfl_xor(term, s, 64);
    if ((tid & 63) == 0) fin[wave] = term;
    __syncthreads();
    if (tid == 0) out[b] = M + __logf(fin[0] + fin[1] + fin[2] + fin[3]);
}

extern "C" void kernel_launch(void* const* d_in, const int* in_sizes, int n_in,
                              void* d_out, int out_size, void* d_ws, size_t ws_size,
                              hipStream_t stream) {
    const float* h       = (const float*)d_in[0];
    const int*   lengths = (const int*)d_in[1];
    const float* trans   = (const float*)d_in[2];
    float*       out     = (float*)d_out;
    (void)in_sizes; (void)n_in; (void)out_size; (void)d_ws; (void)ws_size;

    crf_fwd_kernel<<<Bb, 256, 0, stream>>>(h, lengths, trans, out);
}